// Round 3
// baseline (29.858 us; speedup 1.0000x reference)
//
#include <hip/hip_runtime.h>

// MyMarginLoss: loss = sum_{b,m: mask_mentions} [ sum_c (mask_cand & c!=t) *
//                 max(0, 1.5 - (s[t] - s[c])) ] / (C-1)
// B=128, M=256, C=1024, fp32 source, int32 masks (harness-converted).
// Memory-bound: ~134 MB effective traffic (inactive rows skipped untouched).
//
// Structure: 1 block per 16 rows. Flags+targets for the chunk loaded once
// (lanes 0-15 + ballot); wave w processes the (w+4j)-th ACTIVE rows, so the
// only per-row memory ops are the 8 coalesced vector loads. v_target is
// extracted from the loaded registers (no dependent global gather). The
// target-slot exclusion is a constant -margin correction (its mask is
// guaranteed set by the reference; hinge(t) == margin exactly).

constexpr int kC = 1024;
constexpr float kMargin = 1.5f;
constexpr int kRowsPerBlock = 16;

__global__ __launch_bounds__(256)
void margin_kernel(const float* __restrict__ source,
                   const int* __restrict__ target,
                   const int* __restrict__ mask_mentions,
                   const int* __restrict__ mask_candidates,
                   float* __restrict__ partials)
{
    const int lane = threadIdx.x & 63;
    const int wid  = threadIdx.x >> 6;
    const int row0 = blockIdx.x * kRowsPerBlock;

    // chunk metadata, loaded once per wave (redundant across waves; L2-hot)
    int flag = 0, tval = 0;
    if (lane < kRowsPerBlock) {
        flag = mask_mentions[row0 + lane];
        tval = target[row0 + lane];
    }
    const unsigned mask16 = (unsigned)(__ballot(flag != 0) & 0xFFFFull);

    // wave `wid` takes active rows of rank wid, wid+4, wid+8, ...
    unsigned mm = mask16;
    for (int i = 0; i < wid; ++i) mm &= mm - 1;

    float acc = 0.0f;
    while (mm) {
        const int pos = __ffs(mm) - 1;          // this wave's next active row
        #pragma unroll
        for (int k = 0; k < 4; ++k) mm &= mm - 1;  // advance 4 ranks

        const int row = row0 + pos;
        const int t   = __shfl(tval, pos, 64);  // uniform broadcast, no load

        const float4* __restrict__ sp =
            reinterpret_cast<const float4*>(source + (size_t)row * kC);
        const int4*   __restrict__ mp =
            reinterpret_cast<const int4*>(mask_candidates + (size_t)row * kC);

        // 8 independent 1KB-per-wave loads; nothing else touches memory
        const float4 s0 = sp[lane],       s1 = sp[lane + 64],
                     s2 = sp[lane + 128], s3 = sp[lane + 192];
        const int4   m0 = mp[lane],       m1 = mp[lane + 64],
                     m2 = mp[lane + 128], m3 = mp[lane + 192];

        // v_t from registers: elem t lives at rep=t>>8, lane=(t>>2)&63, k=t&3
        const int rep = t >> 8, li = (t >> 2) & 63, kk = t & 3;
        const float4 sr = (rep == 0) ? s0 : (rep == 1) ? s1
                                          : (rep == 2) ? s2 : s3;   // uniform
        const float cand = (kk == 0) ? sr.x : (kk == 1) ? sr.y
                                            : (kk == 2) ? sr.z : sr.w;
        const float base = kMargin - __shfl(cand, li, 64);

        float racc = 0.0f;
        racc += (m0.x != 0) ? fmaxf(0.0f, base + s0.x) : 0.0f;
        racc += (m0.y != 0) ? fmaxf(0.0f, base + s0.y) : 0.0f;
        racc += (m0.z != 0) ? fmaxf(0.0f, base + s0.z) : 0.0f;
        racc += (m0.w != 0) ? fmaxf(0.0f, base + s0.w) : 0.0f;
        racc += (m1.x != 0) ? fmaxf(0.0f, base + s1.x) : 0.0f;
        racc += (m1.y != 0) ? fmaxf(0.0f, base + s1.y) : 0.0f;
        racc += (m1.z != 0) ? fmaxf(0.0f, base + s1.z) : 0.0f;
        racc += (m1.w != 0) ? fmaxf(0.0f, base + s1.w) : 0.0f;
        racc += (m2.x != 0) ? fmaxf(0.0f, base + s2.x) : 0.0f;
        racc += (m2.y != 0) ? fmaxf(0.0f, base + s2.y) : 0.0f;
        racc += (m2.z != 0) ? fmaxf(0.0f, base + s2.z) : 0.0f;
        racc += (m2.w != 0) ? fmaxf(0.0f, base + s2.w) : 0.0f;
        racc += (m3.x != 0) ? fmaxf(0.0f, base + s3.x) : 0.0f;
        racc += (m3.y != 0) ? fmaxf(0.0f, base + s3.y) : 0.0f;
        racc += (m3.z != 0) ? fmaxf(0.0f, base + s3.z) : 0.0f;
        racc += (m3.w != 0) ? fmaxf(0.0f, base + s3.w) : 0.0f;

        // remove the target slot's guaranteed contribution (exactly kMargin)
        if (lane == 0) racc -= kMargin;
        acc += racc;
    }

    // wave-64 butterfly + one LDS combine per block
    #pragma unroll
    for (int off = 32; off > 0; off >>= 1)
        acc += __shfl_down(acc, off, 64);

    __shared__ float wsum[4];
    if (lane == 0) wsum[wid] = acc;
    __syncthreads();
    if (threadIdx.x == 0)
        partials[blockIdx.x] = wsum[0] + wsum[1] + wsum[2] + wsum[3];
}

// Deterministic final fold of the 2048 per-block partials (8 KB, L2-hot).
__global__ __launch_bounds__(256)
void reduce_kernel(const float* __restrict__ partials, int n,
                   float* __restrict__ out)
{
    float acc = 0.0f;
    for (int i = threadIdx.x; i < n; i += 256)
        acc += partials[i];
    #pragma unroll
    for (int off = 32; off > 0; off >>= 1)
        acc += __shfl_down(acc, off, 64);
    __shared__ float wsum[4];
    const int lane = threadIdx.x & 63;
    const int wid  = threadIdx.x >> 6;
    if (lane == 0) wsum[wid] = acc;
    __syncthreads();
    if (threadIdx.x == 0)
        out[0] = (wsum[0] + wsum[1] + wsum[2] + wsum[3]) * (1.0f / (kC - 1));
}

extern "C" void kernel_launch(void* const* d_in, const int* in_sizes, int n_in,
                              void* d_out, int out_size, void* d_ws, size_t ws_size,
                              hipStream_t stream) {
    const float* source          = (const float*)d_in[0];
    const int*   target          = (const int*)d_in[1];
    const int*   mask_mentions   = (const int*)d_in[2];
    const int*   mask_candidates = (const int*)d_in[3];
    const int n_rows = in_sizes[1];                  // B*M = 32768
    const int n_blocks = n_rows / kRowsPerBlock;     // 2048
    float* partials = (float*)d_ws;                  // 8 KB scratch

    margin_kernel<<<n_blocks, 256, 0, stream>>>(
        source, target, mask_mentions, mask_candidates, partials);
    reduce_kernel<<<1, 256, 0, stream>>>(partials, n_blocks, (float*)d_out);
}